// Round 7
// baseline (377.671 us; speedup 1.0000x reference)
//
#include <hip/hip_runtime.h>
#include <hip/hip_bf16.h>
#include <math.h>

// Problem constants (fixed by the reference)
#define NT    10000      // total nodes (BL*N)
#define NE    120000     // edges
#define HEADS 4
#define MP    10240      // NT padded to 80*128 (GEMM row tiles, XCD-slab swizzle)

using h8    = __attribute__((ext_vector_type(8))) _Float16;
using h4    = __attribute__((ext_vector_type(4))) _Float16;
using f32x4 = __attribute__((ext_vector_type(4))) float;

// ---------------------------------------------------------------------------
// CSR build: histogram by dst -> exclusive scan -> scatter (src, weight)
// ---------------------------------------------------------------------------
__global__ void hist_kernel(const int* __restrict__ dst, int* __restrict__ cnt, int E) {
    int e = blockIdx.x * 256 + threadIdx.x;
    if (e < E) atomicAdd(&cnt[dst[e]], 1);
}

__global__ __launch_bounds__(1024) void scan_kernel(const int* __restrict__ cnt,
                                                    int* __restrict__ rowptr, int n) {
    __shared__ int part[1024];
    int tid = threadIdx.x;
    const int PER = (n + 1023) / 1024 + 1;
    int base = tid * PER;
    int s = 0;
    for (int i = 0; i < PER; ++i) {
        int idx = base + i;
        if (idx < n) s += cnt[idx];
    }
    part[tid] = s;
    __syncthreads();
    for (int off = 1; off < 1024; off <<= 1) {
        int v = (tid >= off) ? part[tid - off] : 0;
        __syncthreads();
        part[tid] += v;
        __syncthreads();
    }
    int run = (tid == 0) ? 0 : part[tid - 1];
    for (int i = 0; i < PER; ++i) {
        int idx = base + i;
        if (idx < n) { rowptr[idx] = run; run += cnt[idx]; }
        else if (idx == n) rowptr[idx] = run;
    }
}

__global__ void scatter_kernel(const int* __restrict__ src, const int* __restrict__ dst,
                               const float* __restrict__ ew,
                               const int* __restrict__ rowptr, int* __restrict__ cursor,
                               int* __restrict__ csr_src, float* __restrict__ csr_w, int E) {
    int e = blockIdx.x * 256 + threadIdx.x;
    if (e >= E) return;
    int d = dst[e];
    int pos = atomicAdd(&cursor[d], 1);
    int idx = rowptr[d] + pos;
    csr_src[idx] = src[e];
    csr_w[idx]  = ew[e];
}

// ---------------------------------------------------------------------------
// fp32 -> (hi,lo) fp16 split, elementwise (for the input x)
// ---------------------------------------------------------------------------
__global__ void split_kernel(const float* __restrict__ X, _Float16* __restrict__ hi,
                             _Float16* __restrict__ lo, int n) {
    int i = blockIdx.x * 256 + threadIdx.x;
    if (i < n) {
        float v = X[i];
        _Float16 h = (_Float16)v;
        hi[i] = h;
        lo[i] = (_Float16)(v - (float)h);
    }
}

// ---------------------------------------------------------------------------
// Fused weight transpose + split for all 6 matrices in ONE dispatch.
// W[K][N] fp32 -> WT_hi[N][K], WT_lo[N][K] fp16. grid = (256, 6).
// ---------------------------------------------------------------------------
struct WsplitArgs {
    const float* W[6];
    _Float16* hi[6];
    _Float16* lo[6];
    int K[6];
    int N[6];
};

__global__ void wsplit_all_kernel(WsplitArgs a) {
    int mat = blockIdx.y;
    int K = a.K[mat], N = a.N[mat];
    int tiles_k = K >> 5;
    int tk = blockIdx.x % tiles_k;
    int tn = blockIdx.x / tiles_k;
    if (tn >= (N >> 5)) return;
    const float* W = a.W[mat];
    _Float16* Thi = a.hi[mat];
    _Float16* Tlo = a.lo[mat];

    __shared__ float t[32][33];
    int bk = tk * 32, bn = tn * 32;
    int tx = threadIdx.x, ty = threadIdx.y;   // (32, 8)
    #pragma unroll
    for (int i = 0; i < 4; ++i)
        t[ty * 4 + i][tx] = W[(size_t)(bk + ty * 4 + i) * N + bn + tx];
    __syncthreads();
    #pragma unroll
    for (int i = 0; i < 4; ++i) {
        int nn = ty * 4 + i;
        float v = t[tx][nn];
        _Float16 h = (_Float16)v;
        Thi[(size_t)(bn + nn) * K + bk + tx] = h;
        Tlo[(size_t)(bn + nn) * K + bk + tx] = (_Float16)(v - (float)h);
    }
}

// ---------------------------------------------------------------------------
// Split-fp16 MFMA GEMM, Wl & Wr fused, DOUBLE-BUFFERED LDS K-loop.
// Block tile 128x128, BK=32, 4 waves, wave tile 64x64.
// Per step: prefetch tile s+1 into buf[!par] (8 glds, wave-owns-buffer,
// fragment-contiguous so ds_read_b128 is conflict-free), then ds_read+MFMA
// on buf[par], then ONE barrier. The barrier's vmcnt(0) drain lands after
// ~430 cyc of compute issue -> load latency overlapped, not exposed.
// XCD-slab swizzle: linear%8 = XCD owns a 10-row-tile A slab (L2-resident).
// D = Ah*Bh + Ah*Bl + Al*Bh (~22-bit mantissa). Output fp16.
// ---------------------------------------------------------------------------
#define BM 128
#define BN 128
#define BK 32
#define CHUNK (BM * BK)   // 4096 halves = 8 KB per sub-buffer

__global__ __launch_bounds__(256, 2) void gemm_mfma_kernel(
    const _Float16* __restrict__ Ahi, const _Float16* __restrict__ Alo,
    const _Float16* __restrict__ WlThi, const _Float16* __restrict__ WlTlo,
    const _Float16* __restrict__ WrThi, const _Float16* __restrict__ WrTlo,
    const float* __restrict__ biasl, const float* __restrict__ biasr,
    _Float16* __restrict__ outl, _Float16* __restrict__ outr,
    int M, int N, int K)
{
    // [parity][buffer: Ahi,Alo,Bhi,Blo][chunk]
    __shared__ _Float16 smem[2][4][CHUNK];    // 64 KB

    int tid = threadIdx.x;
    int wave = tid >> 6, lane = tid & 63;

    // XCD-slab swizzle
    int linear = blockIdx.y * gridDim.x + blockIdx.x;
    int xcd = linear & 7;
    int k   = linear >> 3;
    int r   = k % 10;
    int byy = k / 10;
    int bm  = (xcd * 10 + r) * BM;

    int nby = N >> 7;
    bool isR = byy >= nby;
    int bnn = (isR ? byy - nby : byy) << 7;
    const _Float16* Bh = isR ? WrThi : WlThi;
    const _Float16* Bl = isR ? WrTlo : WlTlo;
    const float* bias  = isR ? biasr : biasl;
    _Float16* out      = isR ? outr : outl;

    // wave w stages buffer w (branchless)
    const _Float16* gsrc = (wave == 0) ? Ahi : (wave == 1) ? Alo : (wave == 2) ? Bh : Bl;
    int rowbase = (wave < 2) ? bm : bnn;

    int lr15 = lane & 15;        // staging: source row within 16-row chunk
    int lk8  = (lane >> 4) * 8;  // staging: source k offset (halves)
    int fq = lane >> 4;
    int fc = lane & 15;
    int wm = (wave & 1) << 6;    // wave sub-tile: 64 rows
    int wn = (wave >> 1) << 6;   // 64 cols

    f32x4 acc[4][4] = {};

    const int NS = K / BK;

    // ---- prologue: stage tile 0 into parity 0
    #pragma unroll
    for (int q = 0; q < 8; ++q) {
        const _Float16* gp = gsrc + (size_t)(rowbase + q * 16 + lr15) * K + lk8;
        __builtin_amdgcn_global_load_lds(
            (const __attribute__((address_space(1))) void*)gp,
            (__attribute__((address_space(3))) void*)(&smem[0][wave][q * 512]),
            16, 0, 0);
    }
    __syncthreads();

    for (int s = 0; s < NS; ++s) {
        int par = s & 1;
        // ---- prefetch tile s+1 into the other parity (no wait here)
        if (s + 1 < NS) {
            int k0 = (s + 1) * BK;
            #pragma unroll
            for (int q = 0; q < 8; ++q) {
                const _Float16* gp = gsrc + (size_t)(rowbase + q * 16 + lr15) * K + k0 + lk8;
                __builtin_amdgcn_global_load_lds(
                    (const __attribute__((address_space(1))) void*)gp,
                    (__attribute__((address_space(3))) void*)(&smem[par ^ 1][wave][q * 512]),
                    16, 0, 0);
            }
        }

        // ---- compute on current parity
        const _Float16* sAhi = smem[par][0];
        const _Float16* sAlo = smem[par][1];
        const _Float16* sBhi = smem[par][2];
        const _Float16* sBlo = smem[par][3];

        h8 ah[4], al[4];
        #pragma unroll
        for (int i = 0; i < 4; ++i) {
            int c = (wave & 1) * 4 + i;
            ah[i] = *(const h8*)(sAhi + c * 512 + lane * 8);
            al[i] = *(const h8*)(sAlo + c * 512 + lane * 8);
        }
        #pragma unroll
        for (int j = 0; j < 4; ++j) {
            int c = (wave >> 1) * 4 + j;
            h8 bh = *(const h8*)(sBhi + c * 512 + lane * 8);
            h8 bl = *(const h8*)(sBlo + c * 512 + lane * 8);
            #pragma unroll
            for (int i = 0; i < 4; ++i) {
                acc[i][j] = __builtin_amdgcn_mfma_f32_16x16x32_f16(ah[i], bh, acc[i][j], 0, 0, 0);
                acc[i][j] = __builtin_amdgcn_mfma_f32_16x16x32_f16(ah[i], bl, acc[i][j], 0, 0, 0);
                acc[i][j] = __builtin_amdgcn_mfma_f32_16x16x32_f16(al[i], bh, acc[i][j], 0, 0, 0);
            }
        }
        __syncthreads();   // drains prefetch vmcnt (overlapped by the MFMA above)
    }

    // epilogue: C/D layout col=lane&15, row=(lane>>4)*4+reg; fp16 store
    #pragma unroll
    for (int j = 0; j < 4; ++j) {
        int col = bnn + wn + j * 16 + fc;
        float bv = bias[col];
        #pragma unroll
        for (int i = 0; i < 4; ++i) {
            int row0 = bm + wm + i * 16 + fq * 4;
            #pragma unroll
            for (int reg = 0; reg < 4; ++reg) {
                int row = row0 + reg;
                if (row < M)
                    out[(size_t)row * N + col] = (_Float16)(acc[i][j][reg] + bv);
            }
        }
    }
}

// ---------------------------------------------------------------------------
// Fused edge attention, all heads in one wave per node; xl/xr are fp16
// (16 B/lane/edge gather). Math in fp32. Online softmax, single pass.
// ---------------------------------------------------------------------------
template<int C, int H, bool DO_ELU, bool SPLIT>
__global__ __launch_bounds__(256) void edge_attn_kernel(
    const _Float16* __restrict__ xl, const _Float16* __restrict__ xr,
    const int* __restrict__ rowptr, const int* __restrict__ csr_src,
    const float* __restrict__ csr_w,
    const float* __restrict__ We, const float* __restrict__ att,
    const float* __restrict__ bias,
    float* __restrict__ out, _Float16* __restrict__ out_hi,
    _Float16* __restrict__ out_lo, int nt)
{
    constexpr int CHT = C * H;        // flat channels per node (512 or 256)
    constexpr int VPT = CHT / 64;     // channels per lane (8 or 4)
    constexpr int G   = 64 / H;       // lanes per head group (16 or 64)

    int node = (blockIdx.x * 256 + threadIdx.x) >> 6;
    int lane = threadIdx.x & 63;
    if (node >= nt) return;
    int c0 = lane * VPT;

    size_t nbase = (size_t)node * CHT + c0;

    float xr_reg[VPT], we_reg[VPT], att_reg[VPT], bias_reg[VPT];
    if (VPT == 8) {
        h8 t = *(const h8*)(xr + nbase);
        #pragma unroll
        for (int v = 0; v < 8; ++v) xr_reg[v] = (float)t[v];
    } else {
        h4 t = *(const h4*)(xr + nbase);
        #pragma unroll
        for (int v = 0; v < VPT; ++v) xr_reg[v] = (float)t[v];
    }
    #pragma unroll
    for (int v = 0; v < VPT; v += 4) {
        *(float4*)(we_reg + v)   = *(const float4*)(We + c0 + v);
        *(float4*)(att_reg + v)  = *(const float4*)(att + c0 + v);
        *(float4*)(bias_reg + v) = *(const float4*)(bias + c0 + v);
    }

    int rs = rowptr[node];
    int re = rowptr[node + 1];

    float m = -INFINITY;
    float ssum = 0.f;
    float av[VPT];
    #pragma unroll
    for (int v = 0; v < VPT; ++v) av[v] = 0.f;

    for (int i = rs; i < re; ++i) {
        int s = csr_src[i];
        float w = csr_w[i];
        const _Float16* xlp = xl + (size_t)s * CHT + c0;
        float xlv[VPT];
        if (VPT == 8) {
            h8 t = *(const h8*)xlp;
            #pragma unroll
            for (int v = 0; v < 8; ++v) xlv[v] = (float)t[v];
        } else {
            h4 t = *(const h4*)xlp;
            #pragma unroll
            for (int v = 0; v < VPT; ++v) xlv[v] = (float)t[v];
        }

        float part = 0.f;
        #pragma unroll
        for (int v = 0; v < VPT; ++v) {
            float t = xlv[v] + xr_reg[v] + w * we_reg[v];
            t = fmaxf(t, 0.f) + 0.2f * fminf(t, 0.f);
            part += t * att_reg[v];
        }
        #pragma unroll
        for (int off = G / 2; off > 0; off >>= 1)
            part += __shfl_xor(part, off, 64);

        float newm = fmaxf(m, part);
        float fac = __expf(m - newm);
        float p = __expf(part - newm);
        ssum = ssum * fac + p;
        #pragma unroll
        for (int v = 0; v < VPT; ++v) av[v] = av[v] * fac + p * xlv[v];
        m = newm;
    }

    float inv = 1.f / (ssum + 1e-16f);
    #pragma unroll
    for (int v = 0; v < VPT; ++v) {
        float o = av[v] * inv + bias_reg[v];
        if (DO_ELU) o = (o > 0.f) ? o : (__expf(o) - 1.f);
        if (SPLIT) {
            _Float16 hh = (_Float16)o;
            out_hi[nbase + v] = hh;
            out_lo[nbase + v] = (_Float16)(o - (float)hh);
        } else {
            out[nbase + v] = o;
        }
    }
}

// ---------------------------------------------------------------------------
extern "C" void kernel_launch(void* const* d_in, const int* in_sizes, int n_in,
                              void* d_out, int out_size, void* d_ws, size_t ws_size,
                              hipStream_t stream) {
    const float* x   = (const float*)d_in[0];
    const int*   ei  = (const int*)d_in[1];
    const float* ew  = (const float*)d_in[2];
    const int* srcp = ei;
    const int* dstp = ei + NE;

    const float* Wl[3]; const float* bl[3]; const float* Wr[3]; const float* br[3];
    const float* We[3]; const float* at[3]; const float* bi[3];
    for (int l = 0; l < 3; ++l) {
        int b = 3 + 7 * l;
        Wl[l] = (const float*)d_in[b + 0];
        bl[l] = (const float*)d_in[b + 1];
        Wr[l] = (const float*)d_in[b + 2];
        br[l] = (const float*)d_in[b + 3];
        We[l] = (const float*)d_in[b + 4];
        at[l] = (const float*)d_in[b + 5];
        bi[l] = (const float*)d_in[b + 6];
    }

    size_t off = 0;
    auto alloc = [&](size_t bytes) -> void* {
        void* p = (char*)d_ws + off;
        off += (bytes + 255) & ~(size_t)255;
        return p;
    };
    _Float16* xl      = (_Float16*)alloc((size_t)MP * 512 * 2);
    _Float16* xr      = (_Float16*)alloc((size_t)MP * 512 * 2);
    _Float16* acthi   = (_Float16*)alloc((size_t)MP * 512 * 2);
    _Float16* actlo   = (_Float16*)alloc((size_t)MP * 512 * 2);
    _Float16* xhi     = (_Float16*)alloc((size_t)MP * 64 * 2);
    _Float16* xlo     = (_Float16*)alloc((size_t)MP * 64 * 2);
    _Float16* wt[3][4];
    const int KD[3] = {64, 512, 512};
    const int ND[3] = {512, 512, 256};
    for (int l = 0; l < 3; ++l)
        for (int q = 0; q < 4; ++q)
            wt[l][q] = (_Float16*)alloc((size_t)KD[l] * ND[l] * 2);
    int*   rowptr  = (int*)alloc((size_t)(NT + 1) * 4);
    int*   cnt     = (int*)alloc((size_t)NT * 4);
    int*   cursor  = (int*)alloc((size_t)NT * 4);
    int*   csr_src = (int*)alloc((size_t)NE * 4);
    float* csr_w   = (float*)alloc((size_t)NE * 4);

    hipMemsetAsync(cnt, 0, (size_t)NT * 4, stream);
    hipMemsetAsync(cursor, 0, (size_t)NT * 4, stream);

    int eblocks = (NE + 255) / 256;
    hist_kernel<<<eblocks, 256, 0, stream>>>(dstp, cnt, NE);
    scan_kernel<<<1, 1024, 0, stream>>>(cnt, rowptr, NT);
    scatter_kernel<<<eblocks, 256, 0, stream>>>(srcp, dstp, ew, rowptr, cursor,
                                                csr_src, csr_w, NE);

    split_kernel<<<(NT * 64 + 255) / 256, 256, 0, stream>>>(x, xhi, xlo, NT * 64);

    // all 6 weight transposes+splits in one dispatch
    {
        WsplitArgs a;
        for (int l = 0; l < 3; ++l) {
            a.W[2 * l]      = Wl[l]; a.hi[2 * l]     = wt[l][0]; a.lo[2 * l]     = wt[l][1];
            a.W[2 * l + 1]  = Wr[l]; a.hi[2 * l + 1] = wt[l][2]; a.lo[2 * l + 1] = wt[l][3];
            a.K[2 * l] = a.K[2 * l + 1] = KD[l];
            a.N[2 * l] = a.N[2 * l + 1] = ND[l];
        }
        dim3 g(256, 6), b(32, 8);
        wsplit_all_kernel<<<g, b, 0, stream>>>(a);
    }

    int nblocks = (NT + 3) / 4;         // one wave per node (edge kernels)

    // ---- Layer 0: K=64, N=512/side, H=4, C=128, ELU
    {
        dim3 g(80, 2 * (512 / BN));     // 640 blocks, XCD-swizzled in-kernel
        gemm_mfma_kernel<<<g, 256, 0, stream>>>(
            xhi, xlo, wt[0][0], wt[0][1], wt[0][2], wt[0][3],
            bl[0], br[0], xl, xr, NT, 512, 64);
        edge_attn_kernel<128, 4, true, true><<<nblocks, 256, 0, stream>>>(
            xl, xr, rowptr, csr_src, csr_w, We[0], at[0], bi[0],
            nullptr, acthi, actlo, NT);
    }

    // ---- Layer 1: K=512, N=512/side
    {
        dim3 g(80, 2 * (512 / BN));
        gemm_mfma_kernel<<<g, 256, 0, stream>>>(
            acthi, actlo, wt[1][0], wt[1][1], wt[1][2], wt[1][3],
            bl[1], br[1], xl, xr, NT, 512, 512);
        edge_attn_kernel<128, 4, true, true><<<nblocks, 256, 0, stream>>>(
            xl, xr, rowptr, csr_src, csr_w, We[1], at[1], bi[1],
            nullptr, acthi, actlo, NT);
    }

    // ---- Layer 2: K=512, N=256/side, H=1, C=256, no ELU -> d_out
    {
        dim3 g(80, 2 * (256 / BN));
        gemm_mfma_kernel<<<g, 256, 0, stream>>>(
            acthi, actlo, wt[2][0], wt[2][1], wt[2][2], wt[2][3],
            bl[2], br[2], xl, xr, NT, 256, 512);
        edge_attn_kernel<256, 1, false, false><<<nblocks, 256, 0, stream>>>(
            xl, xr, rowptr, csr_src, csr_w, We[2], at[2], bi[2],
            (float*)d_out, nullptr, nullptr, NT);
    }
}

// Round 8
// 338.233 us; speedup vs baseline: 1.1166x; 1.1166x over previous
//
#include <hip/hip_runtime.h>
#include <hip/hip_bf16.h>
#include <math.h>

// Problem constants (fixed by the reference)
#define NT    10000      // total nodes (BL*N)
#define NE    120000     // edges
#define HEADS 4
#define MP    10240      // NT padded to 80*128 (GEMM row tiles, XCD-slab swizzle)

using h8    = __attribute__((ext_vector_type(8))) _Float16;
using h4    = __attribute__((ext_vector_type(4))) _Float16;
using f32x4 = __attribute__((ext_vector_type(4))) float;

// ---------------------------------------------------------------------------
// CSR build: histogram by dst -> exclusive scan -> scatter (src, weight)
// ---------------------------------------------------------------------------
__global__ void hist_kernel(const int* __restrict__ dst, int* __restrict__ cnt, int E) {
    int e = blockIdx.x * 256 + threadIdx.x;
    if (e < E) atomicAdd(&cnt[dst[e]], 1);
}

__global__ __launch_bounds__(1024) void scan_kernel(const int* __restrict__ cnt,
                                                    int* __restrict__ rowptr, int n) {
    __shared__ int part[1024];
    int tid = threadIdx.x;
    const int PER = (n + 1023) / 1024 + 1;
    int base = tid * PER;
    int s = 0;
    for (int i = 0; i < PER; ++i) {
        int idx = base + i;
        if (idx < n) s += cnt[idx];
    }
    part[tid] = s;
    __syncthreads();
    for (int off = 1; off < 1024; off <<= 1) {
        int v = (tid >= off) ? part[tid - off] : 0;
        __syncthreads();
        part[tid] += v;
        __syncthreads();
    }
    int run = (tid == 0) ? 0 : part[tid - 1];
    for (int i = 0; i < PER; ++i) {
        int idx = base + i;
        if (idx < n) { rowptr[idx] = run; run += cnt[idx]; }
        else if (idx == n) rowptr[idx] = run;
    }
}

__global__ void scatter_kernel(const int* __restrict__ src, const int* __restrict__ dst,
                               const float* __restrict__ ew,
                               const int* __restrict__ rowptr, int* __restrict__ cursor,
                               int* __restrict__ csr_src, float* __restrict__ csr_w, int E) {
    int e = blockIdx.x * 256 + threadIdx.x;
    if (e >= E) return;
    int d = dst[e];
    int pos = atomicAdd(&cursor[d], 1);
    int idx = rowptr[d] + pos;
    csr_src[idx] = src[e];
    csr_w[idx]  = ew[e];
}

// ---------------------------------------------------------------------------
// fp32 -> (hi,lo) fp16 split, elementwise (for the input x)
// ---------------------------------------------------------------------------
__global__ void split_kernel(const float* __restrict__ X, _Float16* __restrict__ hi,
                             _Float16* __restrict__ lo, int n) {
    int i = blockIdx.x * 256 + threadIdx.x;
    if (i < n) {
        float v = X[i];
        _Float16 h = (_Float16)v;
        hi[i] = h;
        lo[i] = (_Float16)(v - (float)h);
    }
}

// ---------------------------------------------------------------------------
// Fused weight transpose + fp16 round for all 6 matrices in ONE dispatch.
// W[K][N] fp32 -> WT[N][K] fp16 (hi only; fp16 weight rounding contributes
// ~1.4e-4 relative output error -- negligible vs threshold).
// ---------------------------------------------------------------------------
struct WsplitArgs {
    const float* W[6];
    _Float16* hi[6];
    int K[6];
    int N[6];
};

__global__ void wsplit_all_kernel(WsplitArgs a) {
    int mat = blockIdx.y;
    int K = a.K[mat], N = a.N[mat];
    int tiles_k = K >> 5;
    int tk = blockIdx.x % tiles_k;
    int tn = blockIdx.x / tiles_k;
    if (tn >= (N >> 5)) return;
    const float* W = a.W[mat];
    _Float16* Thi = a.hi[mat];

    __shared__ float t[32][33];
    int bk = tk * 32, bn = tn * 32;
    int tx = threadIdx.x, ty = threadIdx.y;   // (32, 8)
    #pragma unroll
    for (int i = 0; i < 4; ++i)
        t[ty * 4 + i][tx] = W[(size_t)(bk + ty * 4 + i) * N + bn + tx];
    __syncthreads();
    #pragma unroll
    for (int i = 0; i < 4; ++i) {
        int nn = ty * 4 + i;
        Thi[(size_t)(bn + nn) * K + bk + tx] = (_Float16)t[tx][nn];
    }
}

// ---------------------------------------------------------------------------
// 2-term split-fp16 MFMA GEMM, Wl & Wr fused. Block tile 128x128, BK=32,
// 4 waves, wave tile 64x64. Single-buffered (dbuf regressed: the compiler's
// vmcnt(0)-before-barrier drains prefetches too). 24 KB LDS + lb(256,4)
// -> 4-5 blocks/CU so barrier drains overlap across resident waves.
// Fragment-contiguous staging: ds_read_b128 conflict-free.
// XCD-slab swizzle: linear%8 = XCD owns a 10-row-tile A slab (L2-resident).
// D = (Ah + Al) * Bh via 2 MFMA accumulations (~22-bit A, fp16 W).
// ---------------------------------------------------------------------------
#define BM 128
#define BN 128
#define BK 32
#define CHUNK (BM * BK)   // 4096 halves = 8 KB per buffer

__global__ __launch_bounds__(256, 4) void gemm_mfma_kernel(
    const _Float16* __restrict__ Ahi, const _Float16* __restrict__ Alo,
    const _Float16* __restrict__ WlT, const _Float16* __restrict__ WrT,
    const float* __restrict__ biasl, const float* __restrict__ biasr,
    _Float16* __restrict__ outl, _Float16* __restrict__ outr,
    int M, int N, int K)
{
    __shared__ _Float16 sAhi[CHUNK];   // 8 KB each, 24 KB total
    __shared__ _Float16 sAlo[CHUNK];
    __shared__ _Float16 sBh[CHUNK];

    int tid = threadIdx.x;
    int wave = tid >> 6, lane = tid & 63;

    // XCD-slab swizzle
    int linear = blockIdx.y * gridDim.x + blockIdx.x;
    int xcd = linear & 7;
    int k   = linear >> 3;
    int r   = k % 10;
    int byy = k / 10;
    int bm  = (xcd * 10 + r) * BM;

    int nby = N >> 7;
    bool isR = byy >= nby;
    int bnn = (isR ? byy - nby : byy) << 7;
    const _Float16* Bh = isR ? WrT : WlT;
    const float* bias  = isR ? biasr : biasl;
    _Float16* out      = isR ? outr : outl;

    int lr15 = lane & 15;        // staging: source row within 16-row chunk
    int lk8  = (lane >> 4) * 8;  // staging: source k offset (halves)
    int fq = lane >> 4;
    int fc = lane & 15;
    int wm = (wave & 1) << 6;    // wave sub-tile: 64 rows
    int wn = (wave >> 1) << 6;   // 64 cols

    f32x4 acc[4][4] = {};

    for (int k0 = 0; k0 < K; k0 += BK) {
        __syncthreads();   // previous iteration's fragment reads complete
        // 24 chunk-loads of 1 KB; wave w stages 6 (wave-uniform bases)
        #pragma unroll
        for (int q = 0; q < 6; ++q) {
            int p = wave * 6 + q;
            const _Float16* g; _Float16* sb; int row;
            if (p < 8)       { g = Ahi; sb = sAhi + p * 512;        row = bm  + p * 16 + lr15; }
            else if (p < 16) { g = Alo; sb = sAlo + (p - 8) * 512;  row = bm  + (p - 8) * 16 + lr15; }
            else             { g = Bh;  sb = sBh  + (p - 16) * 512; row = bnn + (p - 16) * 16 + lr15; }
            const _Float16* gp = g + (size_t)row * K + k0 + lk8;
            __builtin_amdgcn_global_load_lds(
                (const __attribute__((address_space(1))) void*)gp,
                (__attribute__((address_space(3))) void*)sb,
                16, 0, 0);
        }
        __syncthreads();   // staging visible

        h8 ah[4], al[4];
        #pragma unroll
        for (int i = 0; i < 4; ++i) {
            int c = (wave & 1) * 4 + i;
            ah[i] = *(const h8*)(sAhi + c * 512 + lane * 8);
            al[i] = *(const h8*)(sAlo + c * 512 + lane * 8);
        }
        #pragma unroll
        for (int j = 0; j < 4; ++j) {
            int c = (wave >> 1) * 4 + j;
            h8 bh = *(const h8*)(sBh + c * 512 + lane * 8);
            #pragma unroll
            for (int i = 0; i < 4; ++i) {
                acc[i][j] = __builtin_amdgcn_mfma_f32_16x16x32_f16(ah[i], bh, acc[i][j], 0, 0, 0);
                acc[i][j] = __builtin_amdgcn_mfma_f32_16x16x32_f16(al[i], bh, acc[i][j], 0, 0, 0);
            }
        }
    }

    // epilogue: C/D layout col=lane&15, row=(lane>>4)*4+reg; fp16 store
    #pragma unroll
    for (int j = 0; j < 4; ++j) {
        int col = bnn + wn + j * 16 + fc;
        float bv = bias[col];
        #pragma unroll
        for (int i = 0; i < 4; ++i) {
            int row0 = bm + wm + i * 16 + fq * 4;
            #pragma unroll
            for (int reg = 0; reg < 4; ++reg) {
                int row = row0 + reg;
                if (row < M)
                    out[(size_t)row * N + col] = (_Float16)(acc[i][j][reg] + bv);
            }
        }
    }
}

// ---------------------------------------------------------------------------
// Fused edge attention, all heads in one wave per node; xl/xr are fp16
// (16 B/lane/edge gather). Math in fp32. Online softmax, single pass.
// ---------------------------------------------------------------------------
template<int C, int H, bool DO_ELU, bool SPLIT>
__global__ __launch_bounds__(256) void edge_attn_kernel(
    const _Float16* __restrict__ xl, const _Float16* __restrict__ xr,
    const int* __restrict__ rowptr, const int* __restrict__ csr_src,
    const float* __restrict__ csr_w,
    const float* __restrict__ We, const float* __restrict__ att,
    const float* __restrict__ bias,
    float* __restrict__ out, _Float16* __restrict__ out_hi,
    _Float16* __restrict__ out_lo, int nt)
{
    constexpr int CHT = C * H;        // flat channels per node (512 or 256)
    constexpr int VPT = CHT / 64;     // channels per lane (8 or 4)
    constexpr int G   = 64 / H;       // lanes per head group (16 or 64)

    int node = (blockIdx.x * 256 + threadIdx.x) >> 6;
    int lane = threadIdx.x & 63;
    if (node >= nt) return;
    int c0 = lane * VPT;

    size_t nbase = (size_t)node * CHT + c0;

    float xr_reg[VPT], we_reg[VPT], att_reg[VPT], bias_reg[VPT];
    if (VPT == 8) {
        h8 t = *(const h8*)(xr + nbase);
        #pragma unroll
        for (int v = 0; v < 8; ++v) xr_reg[v] = (float)t[v];
    } else {
        h4 t = *(const h4*)(xr + nbase);
        #pragma unroll
        for (int v = 0; v < VPT; ++v) xr_reg[v] = (float)t[v];
    }
    #pragma unroll
    for (int v = 0; v < VPT; v += 4) {
        *(float4*)(we_reg + v)   = *(const float4*)(We + c0 + v);
        *(float4*)(att_reg + v)  = *(const float4*)(att + c0 + v);
        *(float4*)(bias_reg + v) = *(const float4*)(bias + c0 + v);
    }

    int rs = rowptr[node];
    int re = rowptr[node + 1];

    float m = -INFINITY;
    float ssum = 0.f;
    float av[VPT];
    #pragma unroll
    for (int v = 0; v < VPT; ++v) av[v] = 0.f;

    for (int i = rs; i < re; ++i) {
        int s = csr_src[i];
        float w = csr_w[i];
        const _Float16* xlp = xl + (size_t)s * CHT + c0;
        float xlv[VPT];
        if (VPT == 8) {
            h8 t = *(const h8*)xlp;
            #pragma unroll
            for (int v = 0; v < 8; ++v) xlv[v] = (float)t[v];
        } else {
            h4 t = *(const h4*)xlp;
            #pragma unroll
            for (int v = 0; v < VPT; ++v) xlv[v] = (float)t[v];
        }

        float part = 0.f;
        #pragma unroll
        for (int v = 0; v < VPT; ++v) {
            float t = xlv[v] + xr_reg[v] + w * we_reg[v];
            t = fmaxf(t, 0.f) + 0.2f * fminf(t, 0.f);
            part += t * att_reg[v];
        }
        #pragma unroll
        for (int off = G / 2; off > 0; off >>= 1)
            part += __shfl_xor(part, off, 64);

        float newm = fmaxf(m, part);
        float fac = __expf(m - newm);
        float p = __expf(part - newm);
        ssum = ssum * fac + p;
        #pragma unroll
        for (int v = 0; v < VPT; ++v) av[v] = av[v] * fac + p * xlv[v];
        m = newm;
    }

    float inv = 1.f / (ssum + 1e-16f);
    #pragma unroll
    for (int v = 0; v < VPT; ++v) {
        float o = av[v] * inv + bias_reg[v];
        if (DO_ELU) o = (o > 0.f) ? o : (__expf(o) - 1.f);
        if (SPLIT) {
            _Float16 hh = (_Float16)o;
            out_hi[nbase + v] = hh;
            out_lo[nbase + v] = (_Float16)(o - (float)hh);
        } else {
            out[nbase + v] = o;
        }
    }
}

// ---------------------------------------------------------------------------
extern "C" void kernel_launch(void* const* d_in, const int* in_sizes, int n_in,
                              void* d_out, int out_size, void* d_ws, size_t ws_size,
                              hipStream_t stream) {
    const float* x   = (const float*)d_in[0];
    const int*   ei  = (const int*)d_in[1];
    const float* ew  = (const float*)d_in[2];
    const int* srcp = ei;
    const int* dstp = ei + NE;

    const float* Wl[3]; const float* bl[3]; const float* Wr[3]; const float* br[3];
    const float* We[3]; const float* at[3]; const float* bi[3];
    for (int l = 0; l < 3; ++l) {
        int b = 3 + 7 * l;
        Wl[l] = (const float*)d_in[b + 0];
        bl[l] = (const float*)d_in[b + 1];
        Wr[l] = (const float*)d_in[b + 2];
        br[l] = (const float*)d_in[b + 3];
        We[l] = (const float*)d_in[b + 4];
        at[l] = (const float*)d_in[b + 5];
        bi[l] = (const float*)d_in[b + 6];
    }

    size_t off = 0;
    auto alloc = [&](size_t bytes) -> void* {
        void* p = (char*)d_ws + off;
        off += (bytes + 255) & ~(size_t)255;
        return p;
    };
    _Float16* xl      = (_Float16*)alloc((size_t)MP * 512 * 2);
    _Float16* xr      = (_Float16*)alloc((size_t)MP * 512 * 2);
    _Float16* acthi   = (_Float16*)alloc((size_t)MP * 512 * 2);
    _Float16* actlo   = (_Float16*)alloc((size_t)MP * 512 * 2);
    _Float16* xhi     = (_Float16*)alloc((size_t)MP * 64 * 2);
    _Float16* xlo     = (_Float16*)alloc((size_t)MP * 64 * 2);
    _Float16* wt[3][2];   // [layer][{l_hi, r_hi}]
    const int KD[3] = {64, 512, 512};
    const int ND[3] = {512, 512, 256};
    for (int l = 0; l < 3; ++l)
        for (int q = 0; q < 2; ++q)
            wt[l][q] = (_Float16*)alloc((size_t)KD[l] * ND[l] * 2);
    int*   rowptr  = (int*)alloc((size_t)(NT + 1) * 4);
    int*   cnt     = (int*)alloc((size_t)NT * 4);
    int*   cursor  = (int*)alloc((size_t)NT * 4);
    int*   csr_src = (int*)alloc((size_t)NE * 4);
    float* csr_w   = (float*)alloc((size_t)NE * 4);

    hipMemsetAsync(cnt, 0, (size_t)NT * 4, stream);
    hipMemsetAsync(cursor, 0, (size_t)NT * 4, stream);

    int eblocks = (NE + 255) / 256;
    hist_kernel<<<eblocks, 256, 0, stream>>>(dstp, cnt, NE);
    scan_kernel<<<1, 1024, 0, stream>>>(cnt, rowptr, NT);
    scatter_kernel<<<eblocks, 256, 0, stream>>>(srcp, dstp, ew, rowptr, cursor,
                                                csr_src, csr_w, NE);

    split_kernel<<<(NT * 64 + 255) / 256, 256, 0, stream>>>(x, xhi, xlo, NT * 64);

    // all 6 weight transposes (fp16 round) in one dispatch
    {
        WsplitArgs a;
        for (int l = 0; l < 3; ++l) {
            a.W[2 * l]      = Wl[l]; a.hi[2 * l]     = wt[l][0];
            a.W[2 * l + 1]  = Wr[l]; a.hi[2 * l + 1] = wt[l][1];
            a.K[2 * l] = a.K[2 * l + 1] = KD[l];
            a.N[2 * l] = a.N[2 * l + 1] = ND[l];
        }
        dim3 g(256, 6), b(32, 8);
        wsplit_all_kernel<<<g, b, 0, stream>>>(a);
    }

    int nblocks = (NT + 3) / 4;         // one wave per node (edge kernels)

    // ---- Layer 0: K=64, N=512/side, H=4, C=128, ELU
    {
        dim3 g(80, 2 * (512 / BN));     // 640 blocks, XCD-swizzled in-kernel
        gemm_mfma_kernel<<<g, 256, 0, stream>>>(
            xhi, xlo, wt[0][0], wt[0][1],
            bl[0], br[0], xl, xr, NT, 512, 64);
        edge_attn_kernel<128, 4, true, true><<<nblocks, 256, 0, stream>>>(
            xl, xr, rowptr, csr_src, csr_w, We[0], at[0], bi[0],
            nullptr, acthi, actlo, NT);
    }

    // ---- Layer 1: K=512, N=512/side
    {
        dim3 g(80, 2 * (512 / BN));
        gemm_mfma_kernel<<<g, 256, 0, stream>>>(
            acthi, actlo, wt[1][0], wt[1][1],
            bl[1], br[1], xl, xr, NT, 512, 512);
        edge_attn_kernel<128, 4, true, true><<<nblocks, 256, 0, stream>>>(
            xl, xr, rowptr, csr_src, csr_w, We[1], at[1], bi[1],
            nullptr, acthi, actlo, NT);
    }

    // ---- Layer 2: K=512, N=256/side, H=1, C=256, no ELU -> d_out
    {
        dim3 g(80, 2 * (256 / BN));
        gemm_mfma_kernel<<<g, 256, 0, stream>>>(
            acthi, actlo, wt[2][0], wt[2][1],
            bl[2], br[2], xl, xr, NT, 256, 512);
        edge_attn_kernel<256, 1, false, false><<<nblocks, 256, 0, stream>>>(
            xl, xr, rowptr, csr_src, csr_w, We[2], at[2], bi[2],
            (float*)d_out, nullptr, nullptr, NT);
    }
}